// Round 18
// baseline (356.627 us; speedup 1.0000x reference)
//
#include <hip/hip_runtime.h>
#include <stdint.h>

// Problem constants (fixed by the reference)
#define T_TOKENS 16384   // B*S = 4*4096
#define HDIM     2048
#define NEXP     8
#define NCHUNK   (HDIM / 256)                    // 8 chunks of 256 floats
#define TPW      2                               // tokens per wave-iteration
#define WPB      8                               // waves per block (512 threads)
#define NITER    2                               // iterations per wave
#define TOK_PER_BLOCK (WPB * TPW * NITER)        // 32
#define NBLOCKS  (T_TOKENS / TOK_PER_BLOCK)      // 512 = 2 blocks/CU x 256 CUs
                                                 // -> ONE generation, no churn

typedef const __attribute__((address_space(1))) uint32_t* gas_ptr;
typedef __attribute__((address_space(3))) uint32_t*       las_ptr;

__device__ __forceinline__ float dot4(float4 a, float4 b) {
    return a.x * b.x + a.y * b.y + a.z * b.z + a.w * b.w;
}

// Value-splitting butterfly stage: 2*D live accumulators -> D.
template <int D>
__device__ __forceinline__ void reduce_stage(float (&acc)[TPW * NEXP], int lane) {
    const bool upper = (lane & D) != 0;
#pragma unroll
    for (int i = 0; i < D; ++i) {
        float send = upper ? acc[i] : acc[i + D];
        float recv = __shfl_xor(send, D, 64);
        float keep = upper ? acc[i + D] : acc[i];
        acc[i] = keep + recv;
    }
}

// Allocator law (5 measurements): tiers 32/64/128 VGPR; overflow spills, never
// splits tiers. R13's prefetch-before-tail held xv+xn BOTH live in the FMA
// block (~150 regs > 128 tier -> 68 MB scratch). This kernel (fourth
// submission after infra failures -- still unmeasured): streaming loop,
// LOAD-AT-TOP, NO double buffer -- peak live = xv 64 + acc 16 + addr ~10 =
// ~90 < 128 (granted by (512,2)); xv dead across the tail. TLP (16 waves/CU)
// covers the within-wave load->use latency. NITER=2 -> 512 blocks = exactly
// one dispatch generation; gate staged once per CU-slot. '#pragma unroll 1'
// on the loop stops the compiler hoisting iter-1 loads over iter-0's tail
// (which would recreate the fatal double-buffer liveness).
__global__ __launch_bounds__(512, 2) void router_fused(
    const float* __restrict__ x, const float* __restrict__ gate_w,
    float* __restrict__ out, int* __restrict__ gpart) {
    __shared__ float lds_gate[NEXP * HDIM];  // 65536 bytes
    __shared__ int   hist[NEXP];

    const int tid  = threadIdx.x;
    const int lane = tid & 63;
    const int wave = tid >> 6;
    if (tid < NEXP) hist[tid] = 0;

    // Stage gate_w (8x2048 f32 = 64 KB) via async global->LDS DMA: per wave,
    // 8 issues x 1 KB. Zero VGPR round-trip for gate data (verified R5-R14).
    const float4* g4 = (const float4*)gate_w;
    float4* l4 = (float4*)lds_gate;
#pragma unroll
    for (int i = 0; i < (NEXP * HDIM / 4) / 512; ++i) {
        __builtin_amdgcn_global_load_lds(
            (gas_ptr)(g4 + i * 512 + wave * 64 + lane),
            (las_ptr)(l4 + i * 512 + wave * 64), 16, 0, 0);
    }

    const int block_tok = blockIdx.x * TOK_PER_BLOCK;
    const float4* x4 = (const float4*)x;
    const int row = HDIM / 4;  // 512 float4 per token

    __syncthreads();  // gate DMA drained (vmcnt(0)+barrier); hist init visible

#pragma unroll 1
    for (int it = 0; it < NITER; ++it) {
        const int t_base = block_tok + it * (WPB * TPW) + wave * TPW;

        // Load THIS iteration's token pair (16 dwordx4 in flight, max MLP).
        // Consumed by the FMA block below; dead before the tail.
        float4 xv[TPW][NCHUNK];
#pragma unroll
        for (int t = 0; t < TPW; ++t)
#pragma unroll
            for (int c = 0; c < NCHUNK; ++c)
                xv[t][c] = x4[(size_t)(t_base + t) * row + c * 64 + lane];

        float acc[TPW * NEXP];
#pragma unroll
        for (int v = 0; v < TPW * NEXP; ++v) acc[v] = 0.f;

        // Pure LDS + FMA block; all indices compile-time.
#pragma unroll
        for (int c = 0; c < NCHUNK; ++c) {
#pragma unroll
            for (int e = 0; e < NEXP; ++e) {
                float4 gv = l4[e * row + c * 64 + lane];
#pragma unroll
                for (int t = 0; t < TPW; ++t)
                    acc[t * NEXP + e] += dot4(xv[t][c], gv);
            }
        }

        // Cross-lane reduce: 16 values over 64 lanes (bits 0-3), then fold 16/32.
        reduce_stage<8>(acc, lane);
        reduce_stage<4>(acc, lane);
        reduce_stage<2>(acc, lane);
        reduce_stage<1>(acc, lane);
        float v = acc[0];
        v += __shfl_xor(v, 16, 64);
        v += __shfl_xor(v, 32, 64);
        // Lane l holds the full logit for token t_base + ((l>>3)&1), expert l&7.
        const float logit = v;

        // Gather this token-group's 8 logits.
        const int base = lane & 56;
        float lg[NEXP];
#pragma unroll
        for (int e = 0; e < NEXP; ++e) lg[e] = __shfl(logit, base + e, 64);

        // top-2, lowest index wins ties (matches jax.lax.top_k)
        int i1 = 0; float m1 = lg[0];
#pragma unroll
        for (int e = 1; e < NEXP; ++e) {
            if (lg[e] > m1) { m1 = lg[e]; i1 = e; }
        }
        int i2 = 1; float m2 = -3.4e38f;
#pragma unroll
        for (int e = 0; e < NEXP; ++e) {
            if (e != i1 && lg[e] > m2) { m2 = lg[e]; i2 = e; }
        }

        // Renormalized softmax over the top-2 (other experts cancel exactly).
        const float r  = __expf(m2 - m1);  // <= 1
        const float w1 = 1.f / (1.f + r);
        const float w2 = 1.f - w1;

        const bool leader = ((lane & 7) == 0) && (lane < 16);  // lanes 0 and 8
        const int  tok    = t_base + (lane >> 3);
        if (leader) {
            out[tok * 2 + 0] = w1;
            out[tok * 2 + 1] = w2;
            out[2 * T_TOKENS + tok * 2 + 0] = (float)i1;  // indices as f32
            out[2 * T_TOKENS + tok * 2 + 1] = (float)i2;
            // Per-token expert counts into the block-level LDS histogram.
            atomicAdd(&hist[i1], 1);
            atomicAdd(&hist[i2], 1);
        }
    }
    __syncthreads();

    // Plain stores to this block's private slot. No global atomics, no fence.
    if (tid < NEXP) gpart[blockIdx.x * NEXP + tid] = hist[tid];
}

// Reduce the 512x8 partial-histogram table and compute the aux loss.
// Kernel boundary provides the global visibility ordering.
__global__ void router_aux(const int* __restrict__ gpart, float* __restrict__ out) {
    __shared__ int part[256];
    const int t = threadIdx.x;
    int s = 0;
#pragma unroll
    for (int i = 0; i < (NBLOCKS * NEXP) / 256; ++i)  // 16 iters, coalesced
        s += gpart[i * 256 + t];
    part[t] = s;  // thread t's sum is purely expert t&7 (256 % 8 == 0)
    __syncthreads();
    if (t < NEXP) {
        int c = 0;
#pragma unroll
        for (int i = 0; i < 256 / NEXP; ++i) c += part[t + i * NEXP];
        part[t] = c;  // per-expert total
    }
    __syncthreads();
    if (t == 0) {
        float m[NEXP];
        float ssum = 0.f;
#pragma unroll
        for (int e = 0; e < NEXP; ++e) {
            m[e] = (float)part[e] / (float)T_TOKENS;
            ssum += m[e];
        }
        const float mean = ssum / (float)NEXP;
        float var = 0.f;
#pragma unroll
        for (int e = 0; e < NEXP; ++e) {
            float d = m[e] - mean;
            var += d * d;
        }
        var /= (float)(NEXP - 1);            // unbiased (ddof=1), matches torch.var
        out[4 * T_TOKENS] = var * (float)NEXP;
    }
}

extern "C" void kernel_launch(void* const* d_in, const int* in_sizes, int n_in,
                              void* d_out, int out_size, void* d_ws, size_t ws_size,
                              hipStream_t stream) {
    const float* x  = (const float*)d_in[0];
    const float* gw = (const float*)d_in[1];
    float* out = (float*)d_out;
    int* gpart = (int*)d_ws;  // NBLOCKS*NEXP ints = 16 KB; every slot written,
                              // so no memset dispatch needed.

    router_fused<<<NBLOCKS, 512, 0, stream>>>(x, gw, out, gpart);
    router_aux<<<1, 256, 0, stream>>>(gpart, out);
}

// Round 19
// 234.047 us; speedup vs baseline: 1.5237x; 1.5237x over previous
//
#include <hip/hip_runtime.h>
#include <stdint.h>

// Problem constants (fixed by the reference)
#define T_TOKENS 16384   // B*S = 4*4096
#define HDIM     2048
#define NEXP     8
#define NCHUNK   (HDIM / 256)                    // 8 chunks of 256 floats
#define TPW      2                               // tokens per wave-iteration
#define WPB      8                               // waves per block (512 threads)
#define NITER    2                               // iterations per wave
#define TOK_PER_BLOCK (WPB * TPW * NITER)        // 32
#define NBLOCKS  (T_TOKENS / TOK_PER_BLOCK)      // 512 = 2 blocks/CU, 1 generation

typedef const __attribute__((address_space(1))) uint32_t* gas_ptr;
typedef __attribute__((address_space(3))) uint32_t*       las_ptr;

__device__ __forceinline__ float dot4(float4 a, float4 b) {
    return a.x * b.x + a.y * b.y + a.z * b.z + a.w * b.w;
}

// Value-splitting butterfly stage: 2*D live accumulators -> D.
template <int D>
__device__ __forceinline__ void reduce_stage(float (&acc)[TPW * NEXP], int lane) {
    const bool upper = (lane & D) != 0;
#pragma unroll
    for (int i = 0; i < D; ++i) {
        float send = upper ? acc[i] : acc[i + D];
        float recv = __shfl_xor(send, D, 64);
        float keep = upper ? acc[i + D] : acc[i];
        acc[i] = keep + recv;
    }
}

// Seven-structure ledger: every loop-over-token-groups WITHOUT a barrier on
// the back-edge spills catastrophically (R12 196MB / R13 68MB / R18 287MB
// scratch -- '#pragma unroll 1' is NOT a scheduling fence; the compiler
// software-pipelines VMEM across the back-edge and liveness explodes past any
// tier). Every ONE-SHOT BARRIER-PHASED body is clean (R5/R6/R14: VGPR 60,
// WRITE 0.6MB). This kernel: the proven R6 per-iteration body, looped NITER=2
// with __syncthreads() at the END of each iteration as the fence the pragma
// failed to be (forces vmcnt(0) drain at the back-edge -> iter-1 loads cannot
// hoist over iter-0's tail -> cross-iteration liveness ~0). Gate staged ONCE
// per block; 512 blocks = one resident generation (no churn). Bounds (512,4)
// = the bounds of every clean run.
__global__ __launch_bounds__(512, 4) void router_fused(
    const float* __restrict__ x, const float* __restrict__ gate_w,
    float* __restrict__ out, int* __restrict__ gpart) {
    __shared__ float lds_gate[NEXP * HDIM];  // 65536 bytes
    __shared__ int   hist[NEXP];

    const int tid  = threadIdx.x;
    const int lane = tid & 63;
    const int wave = tid >> 6;
    if (tid < NEXP) hist[tid] = 0;

    // Stage gate_w (8x2048 f32 = 64 KB) via async global->LDS DMA: per wave,
    // 8 issues x 1 KB. Zero VGPR round-trip for gate data (verified R5-R14).
    const float4* g4 = (const float4*)gate_w;
    float4* l4 = (float4*)lds_gate;
#pragma unroll
    for (int i = 0; i < (NEXP * HDIM / 4) / 512; ++i) {
        __builtin_amdgcn_global_load_lds(
            (gas_ptr)(g4 + i * 512 + wave * 64 + lane),
            (las_ptr)(l4 + i * 512 + wave * 64), 16, 0, 0);
    }

    const int block_tok = blockIdx.x * TOK_PER_BLOCK;
    const float4* x4 = (const float4*)x;
    const int row = HDIM / 4;  // 512 float4 per token

    __syncthreads();  // gate DMA drained (vmcnt(0)+barrier); hist init visible

#pragma unroll 1
    for (int it = 0; it < NITER; ++it) {
        const int t_base = block_tok + it * (WPB * TPW) + wave * TPW;

        // R6's proven phase body: load this iteration's token pair
        // (16 dwordx4 in flight), consume in FMA block, tail, then FENCE.
        float4 xv[TPW][NCHUNK];
#pragma unroll
        for (int t = 0; t < TPW; ++t)
#pragma unroll
            for (int c = 0; c < NCHUNK; ++c)
                xv[t][c] = x4[(size_t)(t_base + t) * row + c * 64 + lane];

        float acc[TPW * NEXP];
#pragma unroll
        for (int v = 0; v < TPW * NEXP; ++v) acc[v] = 0.f;

        // Pure LDS + FMA block; all indices compile-time.
#pragma unroll
        for (int c = 0; c < NCHUNK; ++c) {
#pragma unroll
            for (int e = 0; e < NEXP; ++e) {
                float4 gv = l4[e * row + c * 64 + lane];
#pragma unroll
                for (int t = 0; t < TPW; ++t)
                    acc[t * NEXP + e] += dot4(xv[t][c], gv);
            }
        }

        // Cross-lane reduce: 16 values over 64 lanes (bits 0-3), then fold 16/32.
        reduce_stage<8>(acc, lane);
        reduce_stage<4>(acc, lane);
        reduce_stage<2>(acc, lane);
        reduce_stage<1>(acc, lane);
        float v = acc[0];
        v += __shfl_xor(v, 16, 64);
        v += __shfl_xor(v, 32, 64);
        // Lane l holds the full logit for token t_base + ((l>>3)&1), expert l&7.
        const float logit = v;

        // Gather this token-group's 8 logits.
        const int base = lane & 56;
        float lg[NEXP];
#pragma unroll
        for (int e = 0; e < NEXP; ++e) lg[e] = __shfl(logit, base + e, 64);

        // top-2, lowest index wins ties (matches jax.lax.top_k)
        int i1 = 0; float m1 = lg[0];
#pragma unroll
        for (int e = 1; e < NEXP; ++e) {
            if (lg[e] > m1) { m1 = lg[e]; i1 = e; }
        }
        int i2 = 1; float m2 = -3.4e38f;
#pragma unroll
        for (int e = 0; e < NEXP; ++e) {
            if (e != i1 && lg[e] > m2) { m2 = lg[e]; i2 = e; }
        }

        // Renormalized softmax over the top-2 (other experts cancel exactly).
        const float r  = __expf(m2 - m1);  // <= 1
        const float w1 = 1.f / (1.f + r);
        const float w2 = 1.f - w1;

        const bool leader = ((lane & 7) == 0) && (lane < 16);  // lanes 0 and 8
        const int  tok    = t_base + (lane >> 3);
        if (leader) {
            out[tok * 2 + 0] = w1;
            out[tok * 2 + 1] = w2;
            out[2 * T_TOKENS + tok * 2 + 0] = (float)i1;  // indices as f32
            out[2 * T_TOKENS + tok * 2 + 1] = (float)i2;
            // Per-token expert counts into the block-level LDS histogram.
            atomicAdd(&hist[i1], 1);
            atomicAdd(&hist[i2], 1);
        }

        // THE FENCE: vmcnt(0)+barrier at the back-edge. Stops the compiler
        // pipelining next iteration's x loads over this tail (the spill
        // mechanism of R12/R13/R18), at the cost R6 already paid per block.
        __syncthreads();
    }

    // All iterations' histogram atomics complete (loop-end barrier).
    // Plain stores to this block's private slot. No global atomics, no fence.
    if (tid < NEXP) gpart[blockIdx.x * NEXP + tid] = hist[tid];
}

// Reduce the 512x8 partial-histogram table and compute the aux loss.
// Kernel boundary provides the global visibility ordering.
__global__ void router_aux(const int* __restrict__ gpart, float* __restrict__ out) {
    __shared__ int part[256];
    const int t = threadIdx.x;
    int s = 0;
#pragma unroll
    for (int i = 0; i < (NBLOCKS * NEXP) / 256; ++i)  // 16 iters, coalesced
        s += gpart[i * 256 + t];
    part[t] = s;  // thread t's sum is purely expert t&7 (256 % 8 == 0)
    __syncthreads();
    if (t < NEXP) {
        int c = 0;
#pragma unroll
        for (int i = 0; i < 256 / NEXP; ++i) c += part[t + i * NEXP];
        part[t] = c;  // per-expert total
    }
    __syncthreads();
    if (t == 0) {
        float m[NEXP];
        float ssum = 0.f;
#pragma unroll
        for (int e = 0; e < NEXP; ++e) {
            m[e] = (float)part[e] / (float)T_TOKENS;
            ssum += m[e];
        }
        const float mean = ssum / (float)NEXP;
        float var = 0.f;
#pragma unroll
        for (int e = 0; e < NEXP; ++e) {
            float d = m[e] - mean;
            var += d * d;
        }
        var /= (float)(NEXP - 1);            // unbiased (ddof=1), matches torch.var
        out[4 * T_TOKENS] = var * (float)NEXP;
    }
}

extern "C" void kernel_launch(void* const* d_in, const int* in_sizes, int n_in,
                              void* d_out, int out_size, void* d_ws, size_t ws_size,
                              hipStream_t stream) {
    const float* x  = (const float*)d_in[0];
    const float* gw = (const float*)d_in[1];
    float* out = (float*)d_out;
    int* gpart = (int*)d_ws;  // NBLOCKS*NEXP ints = 16 KB; every slot written,
                              // so no memset dispatch needed.

    router_fused<<<NBLOCKS, 512, 0, stream>>>(x, gw, out, gpart);
    router_aux<<<1, 256, 0, stream>>>(gpart, out);
}